// Round 1
// baseline (3446.364 us; speedup 1.0000x reference)
//
#include <hip/hip_runtime.h>

#define LEAKY(v) ((v) > 0.0f ? (v) : 0.01f * (v))

constexpr int B_   = 1024;
constexpr int PAD  = 30;
constexpr int E    = 512;
constexpr int IMG  = 2048;
constexpr int C1   = 200;
constexpr int C2   = 300;
constexpr int C3   = 300;
constexpr int LIN2 = 400;
constexpr int FEAT = 2 * C3 + IMG;   // 2648

// ---------------- conv block 1: embed-gather + conv + leaky + zero-gate + maxpool ----
// grid: B*14 blocks, 256 threads. Each block -> one (b, pooled position tp).
__global__ __launch_bounds__(256) void conv1_kernel(
    const int* __restrict__ sent, const float* __restrict__ emb,
    const float* __restrict__ W, const float* __restrict__ bias,
    float* __restrict__ y)
{
    const int blk = blockIdx.x;
    const int b  = blk / 14;
    const int tp = blk % 14;
    const int t0 = 2 * tp;                 // first window start; rows t0..t0+3 needed

    __shared__ float xs[4 * E];            // 4 contiguous embedding rows (8 KB)
    __shared__ float rs[4];                // per-row sums (zero-gate)

    const int tid = threadIdx.x;

    // stage 4 rows of 512 floats via float4 (embed rows are 2KB-aligned)
    for (int idx = tid; idx < 4 * (E / 4); idx += 256) {
        const int r  = idx >> 7;           // E/4 = 128 float4 per row
        const int c4 = idx & 127;
        const int row = sent[b * PAD + t0 + r];
        const float4* src = reinterpret_cast<const float4*>(emb + (size_t)row * E);
        reinterpret_cast<float4*>(xs)[r * 128 + c4] = src[c4];
    }
    __syncthreads();

    const int wid = tid >> 6, lane = tid & 63;
    if (wid < 4) {                          // wave w reduces row w
        float s = 0.f;
        for (int i = lane; i < E; i += 64) s += xs[wid * E + i];
        for (int off = 32; off; off >>= 1) s += __shfl_down(s, off);
        if (lane == 0) rs[wid] = s;
    }
    __syncthreads();

    const int o = tid;
    if (o < C1) {
        const float4* wr = reinterpret_cast<const float4*>(W + (size_t)o * (3 * E));
        const float4* x4 = reinterpret_cast<const float4*>(xs);
        float acc0 = 0.f, acc1 = 0.f;
        #pragma unroll 4
        for (int i = 0; i < (3 * E) / 4; ++i) {
            const float4 w4 = wr[i];
            const float4 a4 = x4[i];            // window t0   = rows 0..2
            const float4 b4 = x4[i + E / 4];    // window t0+1 = rows 1..3
            acc0 += w4.x * a4.x + w4.y * a4.y + w4.z * a4.z + w4.w * a4.w;
            acc1 += w4.x * b4.x + w4.y * b4.y + w4.z * b4.z + w4.w * b4.w;
        }
        const float bia = bias[o];
        float y0 = LEAKY(acc0 + bia);
        float y1v = LEAKY(acc1 + bia);
        if (rs[0] + rs[1] + rs[2] == 0.f) y0  = 0.f;   // zero-gate on window sums
        if (rs[1] + rs[2] + rs[3] == 0.f) y1v = 0.f;
        y[(size_t)(b * 14 + tp) * C1 + o] = fmaxf(y0, y1v);   // maxpool k=2 s=2
    }
}

// ---------------- generic conv block (2 and 3) ----------------------------------
// x: (B, Lin, C) fp32 in workspace; y: (B, Lp, O). grid: B*Lp blocks of BLOCK.
template <int C, int O, int BLOCK>
__global__ __launch_bounds__(BLOCK) void convN_kernel(
    const float* __restrict__ x, const float* __restrict__ W,
    const float* __restrict__ bias, float* __restrict__ y,
    int Lin, int Lp)
{
    const int blk = blockIdx.x;
    const int b  = blk / Lp;
    const int tp = blk % Lp;

    __shared__ float xs[4 * C];
    __shared__ float rs[4];

    const int tid = threadIdx.x;

    // rows 2tp..2tp+3 are contiguous: flat float4 copy of 4C floats (C float4s)
    const float* src = x + ((size_t)b * Lin + 2 * tp) * C;
    for (int i = tid; i < C; i += BLOCK)
        reinterpret_cast<float4*>(xs)[i] = reinterpret_cast<const float4*>(src)[i];
    __syncthreads();

    const int wid = tid >> 6, lane = tid & 63;
    if (wid < 4) {
        float s = 0.f;
        for (int i = lane; i < C; i += 64) s += xs[wid * C + i];
        for (int off = 32; off; off >>= 1) s += __shfl_down(s, off);
        if (lane == 0) rs[wid] = s;
    }
    __syncthreads();

    const int o = tid;
    if (o < O) {
        const float4* wr = reinterpret_cast<const float4*>(W + (size_t)o * (3 * C));
        const float4* x4 = reinterpret_cast<const float4*>(xs);
        float acc0 = 0.f, acc1 = 0.f;
        #pragma unroll 4
        for (int i = 0; i < (3 * C) / 4; ++i) {
            const float4 w4 = wr[i];
            const float4 a4 = x4[i];
            const float4 b4 = x4[i + C / 4];
            acc0 += w4.x * a4.x + w4.y * a4.y + w4.z * a4.z + w4.w * a4.w;
            acc1 += w4.x * b4.x + w4.y * b4.y + w4.z * b4.z + w4.w * b4.w;
        }
        const float bia = bias[o];
        float y0 = LEAKY(acc0 + bia);
        float y1v = LEAKY(acc1 + bia);
        if (rs[0] + rs[1] + rs[2] == 0.f) y0  = 0.f;
        if (rs[1] + rs[2] + rs[3] == 0.f) y1v = 0.f;
        y[(size_t)(b * Lp + tp) * O + o] = fmaxf(y0, y1v);
    }
}

// ---------------- final MLP: concat -> Linear(2648->400) -> leaky -> Linear(400->1)
// grid: B blocks of 256.
__global__ __launch_bounds__(256) void final_kernel(
    const float* __restrict__ y3, const float* __restrict__ img,
    const float* __restrict__ Wm, const float* __restrict__ bm,
    const float* __restrict__ Wo, const float* __restrict__ bo,
    float* __restrict__ out)
{
    const int b = blockIdx.x;
    __shared__ float fs[FEAT];             // 2648 floats
    __shared__ float red[4];

    const int tid = threadIdx.x;

    const float4* s1 = reinterpret_cast<const float4*>(y3 + (size_t)b * (2 * C3));
    for (int i = tid; i < (2 * C3) / 4; i += 256)         // 150 float4
        reinterpret_cast<float4*>(fs)[i] = s1[i];
    const float4* s2 = reinterpret_cast<const float4*>(img + (size_t)b * IMG);
    for (int i = tid; i < IMG / 4; i += 256)              // 512 float4
        reinterpret_cast<float4*>(fs + 2 * C3)[i] = s2[i];
    __syncthreads();

    float partial = 0.f;
    for (int o = tid; o < LIN2; o += 256) {
        const float4* wr = reinterpret_cast<const float4*>(Wm + (size_t)o * FEAT);
        const float4* f4 = reinterpret_cast<const float4*>(fs);
        float acc = 0.f;
        #pragma unroll 4
        for (int i = 0; i < FEAT / 4; ++i) {
            const float4 w4 = wr[i];
            const float4 v4 = f4[i];
            acc += w4.x * v4.x + w4.y * v4.y + w4.z * v4.z + w4.w * v4.w;
        }
        float h = LEAKY(acc + bm[o]);
        partial += h * Wo[o];
    }
    for (int off = 32; off; off >>= 1) partial += __shfl_down(partial, off);
    const int wid = tid >> 6, lane = tid & 63;
    if (lane == 0) red[wid] = partial;
    __syncthreads();
    if (tid == 0) out[b] = red[0] + red[1] + red[2] + red[3] + bo[0];
}

extern "C" void kernel_launch(void* const* d_in, const int* in_sizes, int n_in,
                              void* d_out, int out_size, void* d_ws, size_t ws_size,
                              hipStream_t stream) {
    const float* image = (const float*)d_in[0];
    const int*   sent  = (const int*)  d_in[1];
    const float* emb   = (const float*)d_in[2];
    const float* W1    = (const float*)d_in[3];
    const float* b1    = (const float*)d_in[4];
    const float* W2    = (const float*)d_in[5];
    const float* b2    = (const float*)d_in[6];
    const float* W3    = (const float*)d_in[7];
    const float* b3    = (const float*)d_in[8];
    const float* Wm    = (const float*)d_in[9];
    const float* bm    = (const float*)d_in[10];
    const float* Wo    = (const float*)d_in[11];
    const float* bo    = (const float*)d_in[12];
    float* out = (float*)d_out;

    float* y1 = (float*)d_ws;                         // (B,14,200) = 2,867,200 f
    float* y2 = y1 + (size_t)B_ * 14 * C1;            // (B, 6,300) = 1,843,200 f
    float* y3 = y2 + (size_t)B_ * 6 * C2;             // (B, 2,300) =   614,400 f

    conv1_kernel<<<B_ * 14, 256, 0, stream>>>(sent, emb, W1, b1, y1);
    convN_kernel<C1, C2, 320><<<B_ * 6, 320, 0, stream>>>(y1, W2, b2, y2, 14, 6);
    convN_kernel<C2, C3, 320><<<B_ * 2, 320, 0, stream>>>(y2, W3, b3, y3, 6, 2);
    final_kernel<<<B_, 256, 0, stream>>>(y3, image, Wm, bm, Wo, bo, out);
}

// Round 2
// 1520.152 us; speedup vs baseline: 2.2671x; 2.2671x over previous
//
#include <hip/hip_runtime.h>
#include <hip/hip_bf16.h>

#define LEAKY(v) ((v) > 0.0f ? (v) : 0.01f * (v))

constexpr int B_   = 1024;
constexpr int PAD  = 30;
constexpr int E    = 512;
constexpr int IMG  = 2048;
constexpr int C1   = 200;
constexpr int C2   = 300;
constexpr int C3   = 300;
constexpr int LIN2 = 400;
constexpr int FEAT = 2 * C3 + IMG;   // 2648

constexpr int NT1 = 13;   // N-tiles of 16 (208 >= 200)
constexpr int KT1 = 48;   // K-steps of 32 (1536/32)

typedef __attribute__((ext_vector_type(8))) short bf16x8;
typedef __attribute__((ext_vector_type(4))) float f32x4;

__device__ inline unsigned short f2bf(float f) {
    __hip_bfloat16 h = __float2bfloat16(f);
    return *reinterpret_cast<unsigned short*>(&h);
}
__device__ inline float bf2f(unsigned short u) {
    unsigned int b = ((unsigned int)u) << 16;
    return __uint_as_float(b);
}

// ---- W1 (200,1536) fp32 -> bf16 B-fragment layout [nt][kk][lane][8], zero-pad ch>=200
__global__ __launch_bounds__(256) void convert_w1(const float* __restrict__ W1,
                                                  unsigned short* __restrict__ W1t)
{
    int idx = blockIdx.x * 256 + threadIdx.x;          // (nt*KT1 + kk)*64 + lane
    if (idx >= NT1 * KT1 * 64) return;
    int lane = idx & 63;
    int t    = idx >> 6;
    int kk   = t % KT1;
    int nt   = t / KT1;
    int ch   = nt * 16 + (lane & 15);
    int k0   = kk * 32 + (lane >> 4) * 8;
    ushort4 lo = {0, 0, 0, 0}, hi = {0, 0, 0, 0};
    if (ch < C1) {
        const float4* src = reinterpret_cast<const float4*>(W1 + (size_t)ch * (3 * E) + k0);
        float4 a = src[0], b = src[1];
        lo.x = f2bf(a.x); lo.y = f2bf(a.y); lo.z = f2bf(a.z); lo.w = f2bf(a.w);
        hi.x = f2bf(b.x); hi.y = f2bf(b.y); hi.z = f2bf(b.z); hi.w = f2bf(b.w);
    }
    ushort4* dst = reinterpret_cast<ushort4*>(W1t) + (size_t)idx * 2;
    dst[0] = lo; dst[1] = hi;
}

// ---- conv1 via bf16 MFMA: one block per batch, 4 waves -------------------------
// A = windows of 30 gathered embedding rows (bf16, XOR-swizzled LDS)
// B = W1t fragments from global (coalesced 16B/lane)
// epilogue: bias + leaky + zero-gate + maxpool(k2s2) -> y1 fp32 (B,14,200)
__global__ __launch_bounds__(256) void conv1_mfma(
    const int* __restrict__ sent, const float* __restrict__ emb,
    const unsigned short* __restrict__ W1t, const float* __restrict__ bias,
    float* __restrict__ y)
{
    const int b   = blockIdx.x;
    const int tid = threadIdx.x;
    __shared__ unsigned short xs[32 * E];   // 32 rows x 512 bf16, 16B-chunk swizzled
    __shared__ float rs[32];
    char* xsb = reinterpret_cast<char*>(xs);

    // stage 30 embedding rows, fp32 -> bf16, swizzle 16B chunks: chunk ^= (row&7)
    for (int idx = tid; idx < 30 * 128; idx += 256) {
        int r = idx >> 7, c4 = idx & 127;
        int row = sent[b * PAD + r];
        float4 v = reinterpret_cast<const float4*>(emb + (size_t)row * E)[c4];
        ushort4 h;
        h.x = f2bf(v.x); h.y = f2bf(v.y); h.z = f2bf(v.z); h.w = f2bf(v.w);
        int chunk = c4 >> 1, half = c4 & 1;
        int byteoff = r * 1024 + ((chunk ^ (r & 7)) << 4) + half * 8;
        *reinterpret_cast<ushort4*>(xsb + byteoff) = h;
    }
    // zero rows 30,31 (padding for the second M-tile)
    for (int idx = tid; idx < 2 * 128; idx += 256) {
        int r = 30 + (idx >> 7), c4 = idx & 127;
        int chunk = c4 >> 1, half = c4 & 1;
        int byteoff = r * 1024 + ((chunk ^ (r & 7)) << 4) + half * 8;
        *reinterpret_cast<ushort4*>(xsb + byteoff) = ushort4{0, 0, 0, 0};
    }
    __syncthreads();

    const int wid = tid >> 6, lane = tid & 63;

    // per-row sums (zero-gate), fp32 accumulation over bf16 values
    for (int r = wid; r < 30; r += 4) {
        float s = 0.f;
        #pragma unroll
        for (int j = 0; j < 8; ++j) {
            int e = lane + 64 * j;
            int chunk = e >> 3, within = e & 7;
            int byteoff = r * 1024 + ((chunk ^ (r & 7)) << 4) + within * 2;
            s += bf2f(*reinterpret_cast<unsigned short*>(xsb + byteoff));
        }
        for (int off = 32; off; off >>= 1) s += __shfl_down(s, off);
        if (lane == 0) rs[r] = s;
    }
    __syncthreads();

    const int kg   = lane >> 4;      // 0..3 k-group
    const int trow = lane & 15;      // row within M-tile
    const int g    = lane >> 4;      // C/D row group

    #pragma unroll
    for (int i = 0; i < 4; ++i) {
        int nt = wid + 4 * i;
        if (nt < NT1) {
            f32x4 acc0 = {0, 0, 0, 0}, acc1 = {0, 0, 0, 0};
            const bf16x8* wp = reinterpret_cast<const bf16x8*>(W1t)
                               + (size_t)(nt * KT1) * 64 + lane;
            for (int kk = 0; kk < KT1; ++kk) {
                int chunk  = (kk & 15) * 4 + kg;
                int rowoff = kk >> 4;            // 0..2: which row of the window
                int r0 = trow + rowoff;
                int r1 = trow + 16 + rowoff;
                bf16x8 a0 = *reinterpret_cast<const bf16x8*>(
                    xsb + r0 * 1024 + ((chunk ^ (r0 & 7)) << 4));
                bf16x8 a1 = *reinterpret_cast<const bf16x8*>(
                    xsb + r1 * 1024 + ((chunk ^ (r1 & 7)) << 4));
                bf16x8 bb = wp[kk * 64];
                acc0 = __builtin_amdgcn_mfma_f32_16x16x32_bf16(a0, bb, acc0, 0, 0, 0);
                acc1 = __builtin_amdgcn_mfma_f32_16x16x32_bf16(a1, bb, acc1, 0, 0, 0);
            }
            int ch = nt * 16 + (lane & 15);
            if (ch < C1) {
                float bia = bias[ch];
                #pragma unroll
                for (int mt = 0; mt < 2; ++mt) {
                    #pragma unroll
                    for (int hf = 0; hf < 2; ++hf) {
                        int t0 = mt * 16 + 4 * g + 2 * hf;   // even window index
                        int tp = t0 >> 1;
                        if (tp < 14) {
                            float v0 = (mt ? acc1[2 * hf]     : acc0[2 * hf])     + bia;
                            float v1 = (mt ? acc1[2 * hf + 1] : acc0[2 * hf + 1]) + bia;
                            v0 = LEAKY(v0);
                            v1 = LEAKY(v1);
                            if (rs[t0] + rs[t0 + 1] + rs[t0 + 2] == 0.f) v0 = 0.f;
                            if (rs[t0 + 1] + rs[t0 + 2] + rs[t0 + 3] == 0.f) v1 = 0.f;
                            y[(size_t)(b * 14 + tp) * C1 + ch] = fmaxf(v0, v1);
                        }
                    }
                }
            }
        }
    }
}

// ---------------- generic conv block (2 and 3), fp32 (unchanged) ----------------
template <int C, int O, int BLOCK>
__global__ __launch_bounds__(BLOCK) void convN_kernel(
    const float* __restrict__ x, const float* __restrict__ W,
    const float* __restrict__ bias, float* __restrict__ y,
    int Lin, int Lp)
{
    const int blk = blockIdx.x;
    const int b  = blk / Lp;
    const int tp = blk % Lp;

    __shared__ float xs[4 * C];
    __shared__ float rs[4];

    const int tid = threadIdx.x;

    const float* src = x + ((size_t)b * Lin + 2 * tp) * C;
    for (int i = tid; i < C; i += BLOCK)
        reinterpret_cast<float4*>(xs)[i] = reinterpret_cast<const float4*>(src)[i];
    __syncthreads();

    const int wid = tid >> 6, lane = tid & 63;
    if (wid < 4) {
        float s = 0.f;
        for (int i = lane; i < C; i += 64) s += xs[wid * C + i];
        for (int off = 32; off; off >>= 1) s += __shfl_down(s, off);
        if (lane == 0) rs[wid] = s;
    }
    __syncthreads();

    const int o = tid;
    if (o < O) {
        const float4* wr = reinterpret_cast<const float4*>(W + (size_t)o * (3 * C));
        const float4* x4 = reinterpret_cast<const float4*>(xs);
        float acc0 = 0.f, acc1 = 0.f;
        #pragma unroll 4
        for (int i = 0; i < (3 * C) / 4; ++i) {
            const float4 w4 = wr[i];
            const float4 a4 = x4[i];
            const float4 b4 = x4[i + C / 4];
            acc0 += w4.x * a4.x + w4.y * a4.y + w4.z * a4.z + w4.w * a4.w;
            acc1 += w4.x * b4.x + w4.y * b4.y + w4.z * b4.z + w4.w * b4.w;
        }
        const float bia = bias[o];
        float y0 = LEAKY(acc0 + bia);
        float y1v = LEAKY(acc1 + bia);
        if (rs[0] + rs[1] + rs[2] == 0.f) y0  = 0.f;
        if (rs[1] + rs[2] + rs[3] == 0.f) y1v = 0.f;
        y[(size_t)(b * Lp + tp) * O + o] = fmaxf(y0, y1v);
    }
}

// ---------------- final MLP (unchanged) -----------------------------------------
__global__ __launch_bounds__(256) void final_kernel(
    const float* __restrict__ y3, const float* __restrict__ img,
    const float* __restrict__ Wm, const float* __restrict__ bm,
    const float* __restrict__ Wo, const float* __restrict__ bo,
    float* __restrict__ out)
{
    const int b = blockIdx.x;
    __shared__ float fs[FEAT];
    __shared__ float red[4];

    const int tid = threadIdx.x;

    const float4* s1 = reinterpret_cast<const float4*>(y3 + (size_t)b * (2 * C3));
    for (int i = tid; i < (2 * C3) / 4; i += 256)
        reinterpret_cast<float4*>(fs)[i] = s1[i];
    const float4* s2 = reinterpret_cast<const float4*>(img + (size_t)b * IMG);
    for (int i = tid; i < IMG / 4; i += 256)
        reinterpret_cast<float4*>(fs + 2 * C3)[i] = s2[i];
    __syncthreads();

    float partial = 0.f;
    for (int o = tid; o < LIN2; o += 256) {
        const float4* wr = reinterpret_cast<const float4*>(Wm + (size_t)o * FEAT);
        const float4* f4 = reinterpret_cast<const float4*>(fs);
        float acc = 0.f;
        #pragma unroll 4
        for (int i = 0; i < FEAT / 4; ++i) {
            const float4 w4 = wr[i];
            const float4 v4 = f4[i];
            acc += w4.x * v4.x + w4.y * v4.y + w4.z * v4.z + w4.w * v4.w;
        }
        float h = LEAKY(acc + bm[o]);
        partial += h * Wo[o];
    }
    for (int off = 32; off; off >>= 1) partial += __shfl_down(partial, off);
    const int wid = tid >> 6, lane = tid & 63;
    if (lane == 0) red[wid] = partial;
    __syncthreads();
    if (tid == 0) out[b] = red[0] + red[1] + red[2] + red[3] + bo[0];
}

extern "C" void kernel_launch(void* const* d_in, const int* in_sizes, int n_in,
                              void* d_out, int out_size, void* d_ws, size_t ws_size,
                              hipStream_t stream) {
    const float* image = (const float*)d_in[0];
    const int*   sent  = (const int*)  d_in[1];
    const float* emb   = (const float*)d_in[2];
    const float* W1    = (const float*)d_in[3];
    const float* b1    = (const float*)d_in[4];
    const float* W2    = (const float*)d_in[5];
    const float* b2    = (const float*)d_in[6];
    const float* W3    = (const float*)d_in[7];
    const float* b3    = (const float*)d_in[8];
    const float* Wm    = (const float*)d_in[9];
    const float* bm    = (const float*)d_in[10];
    const float* Wo    = (const float*)d_in[11];
    const float* bo    = (const float*)d_in[12];
    float* out = (float*)d_out;

    float* y1 = (float*)d_ws;                         // (B,14,200)
    float* y2 = y1 + (size_t)B_ * 14 * C1;            // (B, 6,300)
    float* y3 = y2 + (size_t)B_ * 6 * C2;             // (B, 2,300)
    unsigned short* W1t = (unsigned short*)(y3 + (size_t)B_ * 2 * C3);  // 13*48*64*8 bf16

    convert_w1<<<(NT1 * KT1 * 64 + 255) / 256, 256, 0, stream>>>(W1, W1t);
    conv1_mfma<<<B_, 256, 0, stream>>>(sent, emb, W1t, b1, y1);
    convN_kernel<C1, C2, 320><<<B_ * 6, 320, 0, stream>>>(y1, W2, b2, y2, 14, 6);
    convN_kernel<C2, C3, 320><<<B_ * 2, 320, 0, stream>>>(y2, W3, b3, y3, 6, 2);
    final_kernel<<<B_, 256, 0, stream>>>(y3, image, Wm, bm, Wo, bo, out);
}

// Round 3
// 139.624 us; speedup vs baseline: 24.6832x; 10.8875x over previous
//
#include <hip/hip_runtime.h>
#include <hip/hip_bf16.h>

#define LEAKY(v) ((v) > 0.0f ? (v) : 0.01f * (v))

constexpr int B_   = 1024;
constexpr int PAD  = 30;
constexpr int E    = 512;
constexpr int IMG  = 2048;
constexpr int C1   = 200;
constexpr int C2   = 300;
constexpr int C3   = 300;
constexpr int LIN2 = 400;

constexpr int NT1 = 13, KT1 = 48;   // conv1: 208x1536
constexpr int NT2 = 19, KT2 = 21;   // conv2: 304 x (3 rows x 7 steps of 32 in 256-pad)
constexpr int NT3 = 19, KT3 = 30;   // conv3: 304 x (3 rows x 10 steps of 32 in 320-pad)
constexpr int NTM = 25, KTM = 83;   // final: 400 x 2656
constexpr int FK  = 2656;           // feats K padded (2648 -> 2656)

typedef __attribute__((ext_vector_type(8))) short bf16x8;
typedef __attribute__((ext_vector_type(4))) float f32x4;

__device__ inline unsigned short f2bf(float f) {
    __hip_bfloat16 h = __float2bfloat16(f);
    return *reinterpret_cast<unsigned short*>(&h);
}
__device__ inline float bf2f(unsigned short u) {
    unsigned int b = ((unsigned int)u) << 16;
    return __uint_as_float(b);
}

// ================= weight converters: fp32 -> bf16 fragment layout [nt][kk][lane][8]
__global__ __launch_bounds__(256) void convert_w1(const float* __restrict__ W1,
                                                  unsigned short* __restrict__ W1t)
{
    int idx = blockIdx.x * 256 + threadIdx.x;
    if (idx >= NT1 * KT1 * 64) return;
    int lane = idx & 63, t = idx >> 6, kk = t % KT1, nt = t / KT1;
    int ch = nt * 16 + (lane & 15);
    int k0 = kk * 32 + (lane >> 4) * 8;
    ushort4 lo = {0,0,0,0}, hi = {0,0,0,0};
    if (ch < C1) {
        const float4* src = reinterpret_cast<const float4*>(W1 + (size_t)ch * (3*E) + k0);
        float4 a = src[0], b = src[1];
        lo.x=f2bf(a.x); lo.y=f2bf(a.y); lo.z=f2bf(a.z); lo.w=f2bf(a.w);
        hi.x=f2bf(b.x); hi.y=f2bf(b.y); hi.z=f2bf(b.z); hi.w=f2bf(b.w);
    }
    ushort4* dst = reinterpret_cast<ushort4*>(W1t) + (size_t)idx * 2;
    dst[0] = lo; dst[1] = hi;
}

// conv2: K mapped as rowoff*256 + c (c<200 real), kk -> rowoff=kk/7, c0=(kk%7)*32
__global__ __launch_bounds__(256) void convert_w2(const float* __restrict__ W2,
                                                  unsigned short* __restrict__ W2t)
{
    int idx = blockIdx.x * 256 + threadIdx.x;
    if (idx >= NT2 * KT2 * 64) return;
    int lane = idx & 63, t = idx >> 6, kk = t % KT2, nt = t / KT2;
    int ch = nt * 16 + (lane & 15);
    int rowoff = kk / 7;
    int cbase  = (kk % 7) * 32 + (lane >> 4) * 8;
    unsigned short v[8];
    #pragma unroll
    for (int j = 0; j < 8; ++j) {
        int c = cbase + j;
        float f = (ch < C2 && c < C1) ? W2[(size_t)ch * (3*C1) + rowoff * C1 + c] : 0.f;
        v[j] = f2bf(f);
    }
    ushort4* dst = reinterpret_cast<ushort4*>(W2t) + (size_t)idx * 2;
    dst[0] = ushort4{v[0],v[1],v[2],v[3]};
    dst[1] = ushort4{v[4],v[5],v[6],v[7]};
}

// conv3: rowoff=kk/10, c0=(kk%10)*32, c<300 real
__global__ __launch_bounds__(256) void convert_w3(const float* __restrict__ W3,
                                                  unsigned short* __restrict__ W3t)
{
    int idx = blockIdx.x * 256 + threadIdx.x;
    if (idx >= NT3 * KT3 * 64) return;
    int lane = idx & 63, t = idx >> 6, kk = t % KT3, nt = t / KT3;
    int ch = nt * 16 + (lane & 15);
    int rowoff = kk / 10;
    int cbase  = (kk % 10) * 32 + (lane >> 4) * 8;
    unsigned short v[8];
    #pragma unroll
    for (int j = 0; j < 8; ++j) {
        int c = cbase + j;
        float f = (ch < C3 && c < C2) ? W3[(size_t)ch * (3*C2) + rowoff * C2 + c] : 0.f;
        v[j] = f2bf(f);
    }
    ushort4* dst = reinterpret_cast<ushort4*>(W3t) + (size_t)idx * 2;
    dst[0] = ushort4{v[0],v[1],v[2],v[3]};
    dst[1] = ushort4{v[4],v[5],v[6],v[7]};
}

__global__ __launch_bounds__(256) void convert_wm(const float* __restrict__ Wm,
                                                  unsigned short* __restrict__ Wmt)
{
    int idx = blockIdx.x * 256 + threadIdx.x;
    if (idx >= NTM * KTM * 64) return;
    int lane = idx & 63, t = idx >> 6, kk = t % KTM, nt = t / KTM;
    int ch = nt * 16 + (lane & 15);                  // < 400 always
    int kbase = kk * 32 + (lane >> 4) * 8;
    unsigned short v[8];
    #pragma unroll
    for (int j = 0; j < 8; ++j) {
        int k = kbase + j;
        float f = (k < 2648) ? Wm[(size_t)ch * 2648 + k] : 0.f;
        v[j] = f2bf(f);
    }
    ushort4* dst = reinterpret_cast<ushort4*>(Wmt) + (size_t)idx * 2;
    dst[0] = ushort4{v[0],v[1],v[2],v[3]};
    dst[1] = ushort4{v[4],v[5],v[6],v[7]};
}

// ================= conv1 (unchanged, verified) ===================================
__global__ __launch_bounds__(256) void conv1_mfma(
    const int* __restrict__ sent, const float* __restrict__ emb,
    const unsigned short* __restrict__ W1t, const float* __restrict__ bias,
    float* __restrict__ y)
{
    const int b   = blockIdx.x;
    const int tid = threadIdx.x;
    __shared__ unsigned short xs[32 * E];
    __shared__ float rs[32];
    char* xsb = reinterpret_cast<char*>(xs);

    for (int idx = tid; idx < 30 * 128; idx += 256) {
        int r = idx >> 7, c4 = idx & 127;
        int row = sent[b * PAD + r];
        float4 v = reinterpret_cast<const float4*>(emb + (size_t)row * E)[c4];
        ushort4 h;
        h.x = f2bf(v.x); h.y = f2bf(v.y); h.z = f2bf(v.z); h.w = f2bf(v.w);
        int chunk = c4 >> 1, half = c4 & 1;
        int byteoff = r * 1024 + ((chunk ^ (r & 7)) << 4) + half * 8;
        *reinterpret_cast<ushort4*>(xsb + byteoff) = h;
    }
    for (int idx = tid; idx < 2 * 128; idx += 256) {
        int r = 30 + (idx >> 7), c4 = idx & 127;
        int chunk = c4 >> 1, half = c4 & 1;
        int byteoff = r * 1024 + ((chunk ^ (r & 7)) << 4) + half * 8;
        *reinterpret_cast<ushort4*>(xsb + byteoff) = ushort4{0,0,0,0};
    }
    __syncthreads();

    const int wid = tid >> 6, lane = tid & 63;

    for (int r = wid; r < 30; r += 4) {
        float s = 0.f;
        #pragma unroll
        for (int j = 0; j < 8; ++j) {
            int e = lane + 64 * j;
            int chunk = e >> 3, within = e & 7;
            int byteoff = r * 1024 + ((chunk ^ (r & 7)) << 4) + within * 2;
            s += bf2f(*reinterpret_cast<unsigned short*>(xsb + byteoff));
        }
        for (int off = 32; off; off >>= 1) s += __shfl_down(s, off);
        if (lane == 0) rs[r] = s;
    }
    __syncthreads();

    const int kg   = lane >> 4;
    const int trow = lane & 15;
    const int g    = lane >> 4;

    #pragma unroll
    for (int i = 0; i < 4; ++i) {
        int nt = wid + 4 * i;
        if (nt < NT1) {
            f32x4 acc0 = {0,0,0,0}, acc1 = {0,0,0,0};
            const bf16x8* wp = reinterpret_cast<const bf16x8*>(W1t)
                               + (size_t)(nt * KT1) * 64 + lane;
            for (int kk = 0; kk < KT1; ++kk) {
                int chunk  = (kk & 15) * 4 + kg;
                int rowoff = kk >> 4;
                int r0 = trow + rowoff;
                int r1 = trow + 16 + rowoff;
                bf16x8 a0 = *reinterpret_cast<const bf16x8*>(
                    xsb + r0 * 1024 + ((chunk ^ (r0 & 7)) << 4));
                bf16x8 a1 = *reinterpret_cast<const bf16x8*>(
                    xsb + r1 * 1024 + ((chunk ^ (r1 & 7)) << 4));
                bf16x8 bb = wp[kk * 64];
                acc0 = __builtin_amdgcn_mfma_f32_16x16x32_bf16(a0, bb, acc0, 0, 0, 0);
                acc1 = __builtin_amdgcn_mfma_f32_16x16x32_bf16(a1, bb, acc1, 0, 0, 0);
            }
            int ch = nt * 16 + (lane & 15);
            if (ch < C1) {
                float bia = bias[ch];
                #pragma unroll
                for (int mt = 0; mt < 2; ++mt) {
                    #pragma unroll
                    for (int hf = 0; hf < 2; ++hf) {
                        int t0 = mt * 16 + 4 * g + 2 * hf;
                        int tp = t0 >> 1;
                        if (tp < 14) {
                            float v0 = (mt ? acc1[2*hf]   : acc0[2*hf])   + bia;
                            float v1 = (mt ? acc1[2*hf+1] : acc0[2*hf+1]) + bia;
                            v0 = LEAKY(v0);
                            v1 = LEAKY(v1);
                            if (rs[t0] + rs[t0+1] + rs[t0+2] == 0.f) v0 = 0.f;
                            if (rs[t0+1] + rs[t0+2] + rs[t0+3] == 0.f) v1 = 0.f;
                            y[(size_t)(b * 14 + tp) * C1 + ch] = fmaxf(v0, v1);
                        }
                    }
                }
            }
        }
    }
}

// ================= conv2 via MFMA: 1 block/batch ================================
// x: y1 (B,14,200) fp32. LDS rows 256-bf16-padded (512B), XOR-swizzled 16B chunks.
__global__ __launch_bounds__(256) void conv2_mfma(
    const float* __restrict__ x, const unsigned short* __restrict__ Wt,
    const float* __restrict__ bias, float* __restrict__ y)
{
    const int b   = blockIdx.x;
    const int tid = threadIdx.x;
    __shared__ unsigned short xs[18 * 256];
    __shared__ float rs[18];
    char* xsb = reinterpret_cast<char*>(xs);

    for (int idx = tid; idx < 18 * 32; idx += 256) {    // 32 chunks/row of 16B
        int r = idx >> 5, ck = idx & 31;
        ushort4 lo = {0,0,0,0}, hi = {0,0,0,0};
        if (r < 14 && ck < 25) {
            const float4* src = reinterpret_cast<const float4*>(
                x + ((size_t)b * 14 + r) * C1 + ck * 8);
            float4 a = src[0], c = src[1];
            lo.x=f2bf(a.x); lo.y=f2bf(a.y); lo.z=f2bf(a.z); lo.w=f2bf(a.w);
            hi.x=f2bf(c.x); hi.y=f2bf(c.y); hi.z=f2bf(c.z); hi.w=f2bf(c.w);
        }
        int bo_ = r * 512 + ((ck ^ (r & 7)) << 4);
        *reinterpret_cast<ushort4*>(xsb + bo_)     = lo;
        *reinterpret_cast<ushort4*>(xsb + bo_ + 8) = hi;
    }
    __syncthreads();

    const int wid = tid >> 6, lane = tid & 63;
    const int kg = lane >> 4, trow = lane & 15, g = lane >> 4;

    for (int r = wid; r < 14; r += 4) {
        float s = 0.f;
        #pragma unroll
        for (int j = 0; j < 4; ++j) {
            int e = lane + 64 * j;
            int chunk = e >> 3, within = e & 7;
            s += bf2f(*reinterpret_cast<unsigned short*>(
                xsb + r * 512 + ((chunk ^ (r & 7)) << 4) + within * 2));
        }
        for (int off = 32; off; off >>= 1) s += __shfl_down(s, off);
        if (lane == 0) rs[r] = s;
    }
    __syncthreads();

    for (int nt = wid; nt < NT2; nt += 4) {
        f32x4 acc = {0,0,0,0};
        const bf16x8* wp = reinterpret_cast<const bf16x8*>(Wt)
                           + (size_t)(nt * KT2) * 64 + lane;
        int kidx = 0;
        #pragma unroll
        for (int rowoff = 0; rowoff < 3; ++rowoff) {
            #pragma unroll
            for (int cc = 0; cc < 7; ++cc, ++kidx) {
                int r0 = trow + rowoff;
                int chunk = cc * 4 + kg;
                bf16x8 a = *reinterpret_cast<const bf16x8*>(
                    xsb + r0 * 512 + ((chunk ^ (r0 & 7)) << 4));
                bf16x8 bb = wp[kidx * 64];
                acc = __builtin_amdgcn_mfma_f32_16x16x32_bf16(a, bb, acc, 0, 0, 0);
            }
        }
        int ch = nt * 16 + (lane & 15);
        if (ch < C2) {
            float bia = bias[ch];
            #pragma unroll
            for (int hf = 0; hf < 2; ++hf) {
                int t0 = 4 * g + 2 * hf;      // even window index
                if (t0 < 12) {
                    float v0 = LEAKY(acc[2*hf]   + bia);
                    float v1 = LEAKY(acc[2*hf+1] + bia);
                    if (rs[t0] + rs[t0+1] + rs[t0+2] == 0.f) v0 = 0.f;
                    if (rs[t0+1] + rs[t0+2] + rs[t0+3] == 0.f) v1 = 0.f;
                    y[((size_t)b * 6 + (t0 >> 1)) * C2 + ch] = fmaxf(v0, v1);
                }
            }
        }
    }
}

// ================= conv3 via MFMA: 1 block / 4 batches ==========================
// x: y2 (B,6,300) fp32; M-tile = 4 batches x 4 windows. LDS rows 320-bf16 (640B).
__global__ __launch_bounds__(256) void conv3_mfma(
    const float* __restrict__ x, const unsigned short* __restrict__ Wt,
    const float* __restrict__ bias, float* __restrict__ y)
{
    const int b0  = blockIdx.x * 4;
    const int tid = threadIdx.x;
    __shared__ unsigned short xs[24 * 320];
    __shared__ float rs[24];
    char* xsb = reinterpret_cast<char*>(xs);

    for (int idx = tid; idx < 24 * 40; idx += 256) {    // 40 chunks/row
        int r = idx / 40, ck = idx % 40;
        int c0 = ck * 8;
        ushort4 lo = {0,0,0,0}, hi = {0,0,0,0};
        const float* row = x + ((size_t)b0 * 6 + r) * C2;
        if (c0 + 8 <= C2) {
            const float4* src = reinterpret_cast<const float4*>(row + c0);
            float4 a = src[0], c = src[1];
            lo.x=f2bf(a.x); lo.y=f2bf(a.y); lo.z=f2bf(a.z); lo.w=f2bf(a.w);
            hi.x=f2bf(c.x); hi.y=f2bf(c.y); hi.z=f2bf(c.z); hi.w=f2bf(c.w);
        } else if (c0 < C2) {                           // chunk 37: 296..299 valid
            unsigned short v[8];
            #pragma unroll
            for (int j = 0; j < 8; ++j)
                v[j] = (c0 + j < C2) ? f2bf(row[c0 + j]) : (unsigned short)0;
            lo = ushort4{v[0],v[1],v[2],v[3]};
            hi = ushort4{v[4],v[5],v[6],v[7]};
        }
        int bo_ = r * 640 + ((ck ^ (r & 7)) << 4);
        *reinterpret_cast<ushort4*>(xsb + bo_)     = lo;
        *reinterpret_cast<ushort4*>(xsb + bo_ + 8) = hi;
    }
    __syncthreads();

    const int wid = tid >> 6, lane = tid & 63;
    const int kg = lane >> 4, trow = lane & 15, g = lane >> 4;

    for (int r = wid; r < 24; r += 4) {
        float s = 0.f;
        #pragma unroll
        for (int j = 0; j < 5; ++j) {
            int e = lane + 64 * j;
            int chunk = e >> 3, within = e & 7;
            s += bf2f(*reinterpret_cast<unsigned short*>(
                xsb + r * 640 + ((chunk ^ (r & 7)) << 4) + within * 2));
        }
        for (int off = 32; off; off >>= 1) s += __shfl_down(s, off);
        if (lane == 0) rs[r] = s;
    }
    __syncthreads();

    const int rbase = 6 * (trow >> 2) + (trow & 3);     // staged row for m=trow

    for (int nt = wid; nt < NT3; nt += 4) {
        f32x4 acc = {0,0,0,0};
        const bf16x8* wp = reinterpret_cast<const bf16x8*>(Wt)
                           + (size_t)(nt * KT3) * 64 + lane;
        int kidx = 0;
        #pragma unroll
        for (int rowoff = 0; rowoff < 3; ++rowoff) {
            #pragma unroll
            for (int cc = 0; cc < 10; ++cc, ++kidx) {
                int r0 = rbase + rowoff;
                int chunk = cc * 4 + kg;
                bf16x8 a = *reinterpret_cast<const bf16x8*>(
                    xsb + r0 * 640 + ((chunk ^ (r0 & 7)) << 4));
                bf16x8 bb = wp[kidx * 64];
                acc = __builtin_amdgcn_mfma_f32_16x16x32_bf16(a, bb, acc, 0, 0, 0);
            }
        }
        int ch = nt * 16 + (lane & 15);
        if (ch < C3) {
            float bia = bias[ch];
            #pragma unroll
            for (int tp = 0; tp < 2; ++tp) {            // windows t=2tp, 2tp+1 of batch g
                int rb = g * 6 + 2 * tp;
                float v0 = LEAKY(acc[2*tp]   + bia);
                float v1 = LEAKY(acc[2*tp+1] + bia);
                if (rs[rb] + rs[rb+1] + rs[rb+2] == 0.f) v0 = 0.f;
                if (rs[rb+1] + rs[rb+2] + rs[rb+3] == 0.f) v1 = 0.f;
                y[((size_t)(b0 + g) * 2 + tp) * C3 + ch] = fmaxf(v0, v1);
            }
        }
    }
}

// ================= feats concat: [y3 | image] -> bf16 [B][2656] =================
__global__ __launch_bounds__(256) void concat_feats(
    const float* __restrict__ y3, const float* __restrict__ img,
    unsigned short* __restrict__ feats)
{
    const int b = blockIdx.x;
    for (int ck = threadIdx.x; ck < FK / 8; ck += 256) {   // 332 chunks of 8
        int c0 = ck * 8;
        ushort4 lo = {0,0,0,0}, hi = {0,0,0,0};
        const float4* src = nullptr;
        if (c0 + 8 <= 600)      src = reinterpret_cast<const float4*>(y3 + (size_t)b*600 + c0);
        else if (c0 + 8 <= 2648) src = reinterpret_cast<const float4*>(img + (size_t)b*IMG + (c0-600));
        if (src) {
            float4 a = src[0], c = src[1];
            lo.x=f2bf(a.x); lo.y=f2bf(a.y); lo.z=f2bf(a.z); lo.w=f2bf(a.w);
            hi.x=f2bf(c.x); hi.y=f2bf(c.y); hi.z=f2bf(c.z); hi.w=f2bf(c.w);
        }
        ushort4* dst = reinterpret_cast<ushort4*>(feats + (size_t)b * FK + c0);
        dst[0] = lo; dst[1] = hi;
    }
}

// ================= final GEMM: h = leaky(feats @ Wm.T + bm), (1024,400) =========
// wave = one (mt,nt) 16x16 tile; A-fragments straight from global bf16 feats.
__global__ __launch_bounds__(256) void final_mfma(
    const unsigned short* __restrict__ feats, const unsigned short* __restrict__ Wmt,
    const float* __restrict__ bm, float* __restrict__ h)
{
    const int tid = threadIdx.x;
    const int wid = tid >> 6, lane = tid & 63;
    const int gw = blockIdx.x * 4 + wid;          // 0..1599
    const int mt = gw / NTM, nt = gw % NTM;
    const int kg = lane >> 4, trow = lane & 15, g = lane >> 4;
    const int m0 = mt * 16, n0 = nt * 16;

    const bf16x8* ap = reinterpret_cast<const bf16x8*>(feats)
                       + (size_t)(m0 + trow) * (FK / 8) + kg;
    const bf16x8* wp = reinterpret_cast<const bf16x8*>(Wmt)
                       + (size_t)(nt * KTM) * 64 + lane;

    f32x4 acc = {0,0,0,0};
    for (int kk = 0; kk < KTM; ++kk) {
        bf16x8 a  = ap[kk * 4];
        bf16x8 bb = wp[kk * 64];
        acc = __builtin_amdgcn_mfma_f32_16x16x32_bf16(a, bb, acc, 0, 0, 0);
    }
    const int ch = n0 + (lane & 15);
    const float bia = bm[ch];
    #pragma unroll
    for (int reg = 0; reg < 4; ++reg) {
        float v = LEAKY(acc[reg] + bia);
        h[(size_t)(m0 + 4 * g + reg) * LIN2 + ch] = v;
    }
}

// ================= out[b] = h[b] . Wo + bo ======================================
__global__ __launch_bounds__(256) void final_reduce(
    const float* __restrict__ h, const float* __restrict__ Wo,
    const float* __restrict__ bo, float* __restrict__ out)
{
    const int tid = threadIdx.x;
    const int wid = tid >> 6, lane = tid & 63;
    const int b = blockIdx.x * 4 + wid;
    float s = 0.f;
    #pragma unroll
    for (int j = 0; j < 7; ++j) {
        int o = lane + 64 * j;
        if (o < LIN2) s += h[(size_t)b * LIN2 + o] * Wo[o];
    }
    for (int off = 32; off; off >>= 1) s += __shfl_down(s, off);
    if (lane == 0) out[b] = s + bo[0];
}

extern "C" void kernel_launch(void* const* d_in, const int* in_sizes, int n_in,
                              void* d_out, int out_size, void* d_ws, size_t ws_size,
                              hipStream_t stream) {
    const float* image = (const float*)d_in[0];
    const int*   sent  = (const int*)  d_in[1];
    const float* emb   = (const float*)d_in[2];
    const float* W1    = (const float*)d_in[3];
    const float* b1    = (const float*)d_in[4];
    const float* W2    = (const float*)d_in[5];
    const float* b2    = (const float*)d_in[6];
    const float* W3    = (const float*)d_in[7];
    const float* b3    = (const float*)d_in[8];
    const float* Wm    = (const float*)d_in[9];
    const float* bm    = (const float*)d_in[10];
    const float* Wo    = (const float*)d_in[11];
    const float* bo    = (const float*)d_in[12];
    float* out = (float*)d_out;

    // ws layout (floats); y1 region reused for feats, y2 region reused for h
    float* y1 = (float*)d_ws;                          // 2,867,200 f
    float* y2 = y1 + 2867200;                          // 1,843,200 f
    float* y3 = y2 + 1843200;                          //   614,400 f
    unsigned short* W1t = (unsigned short*)(y3 + 614400);   // 319,488 us
    unsigned short* W2t = W1t + NT1*KT1*64*8;                // 204,288 us
    unsigned short* W3t = W2t + NT2*KT2*64*8;                // 291,840 us
    unsigned short* Wmt = W3t + NT3*KT3*64*8;                // 1,062,400 us
    unsigned short* feats = (unsigned short*)y1;             // 2,719,744 us (fits)
    float* h = y2;                                           // 409,600 f (fits)

    convert_w1<<<(NT1*KT1*64 + 255)/256, 256, 0, stream>>>(W1, W1t);
    convert_w2<<<(NT2*KT2*64 + 255)/256, 256, 0, stream>>>(W2, W2t);
    convert_w3<<<(NT3*KT3*64 + 255)/256, 256, 0, stream>>>(W3, W3t);
    convert_wm<<<(NTM*KTM*64 + 255)/256, 256, 0, stream>>>(Wm, Wmt);

    conv1_mfma<<<B_, 256, 0, stream>>>(sent, emb, W1t, b1, y1);
    conv2_mfma<<<B_, 256, 0, stream>>>(y1, W2t, b2, y2);
    conv3_mfma<<<B_/4, 256, 0, stream>>>(y2, W3t, b3, y3);
    concat_feats<<<B_, 256, 0, stream>>>(y3, image, feats);
    final_mfma<<<(64*NTM)/4, 256, 0, stream>>>(feats, Wmt, bm, h);
    final_reduce<<<B_/4, 256, 0, stream>>>(h, Wo, bo, out);
}

// Round 4
// 126.667 us; speedup vs baseline: 27.2082x; 1.1023x over previous
//
#include <hip/hip_runtime.h>
#include <hip/hip_bf16.h>

#define LEAKY(v) ((v) > 0.0f ? (v) : 0.01f * (v))

constexpr int B_   = 1024;
constexpr int PAD  = 30;
constexpr int E    = 512;
constexpr int IMG  = 2048;
constexpr int C1   = 200;
constexpr int C2   = 300;
constexpr int C3   = 300;
constexpr int LIN2 = 400;

constexpr int NT1P = 16, KT1 = 48;   // conv1: 256-pad x 1536
constexpr int NT2P = 20, KT2 = 21;   // conv2: 320-pad x (3x7 steps in 256-pad rows)
constexpr int NT3P = 20, KT3 = 30;   // conv3: 320-pad x (3x10 steps in 320-pad rows)
constexpr int NTMP = 28, KTM = 83;   // final: 448-pad x 2656
constexpr int FK  = 2656;            // feats K padded (2648 -> 2656)

constexpr int T1 = NT1P * KT1;       // 768
constexpr int T2 = NT2P * KT2;       // 420
constexpr int T3 = NT3P * KT3;       // 600
constexpr int TM = NTMP * KTM;       // 2324
constexpr int TTOT = T1 + T2 + T3 + TM;  // 4112

typedef __attribute__((ext_vector_type(8))) short bf16x8;
typedef __attribute__((ext_vector_type(4))) float f32x4;

__device__ inline unsigned short f2bf(float f) {
    __hip_bfloat16 h = __float2bfloat16(f);
    return *reinterpret_cast<unsigned short*>(&h);
}
__device__ inline float bf2f(unsigned short u) {
    unsigned int b = ((unsigned int)u) << 16;
    return __uint_as_float(b);
}

// ================= fused weight converter: fp32 -> bf16 fragments [nt][kk][lane][8]
__global__ __launch_bounds__(256) void convert_all(
    const float* __restrict__ W1, const float* __restrict__ W2,
    const float* __restrict__ W3, const float* __restrict__ Wm,
    unsigned short* __restrict__ W1t, unsigned short* __restrict__ W2t,
    unsigned short* __restrict__ W3t, unsigned short* __restrict__ Wmt)
{
    int idx = blockIdx.x * 256 + threadIdx.x;
    if (idx >= TTOT * 64) return;
    int lane = idx & 63, t = idx >> 6;
    unsigned short v[8];

    if (t < T1) {
        int kk = t % KT1, nt = t / KT1;
        int ch = nt * 16 + (lane & 15);
        int k0 = kk * 32 + (lane >> 4) * 8;
        #pragma unroll
        for (int j = 0; j < 8; ++j)
            v[j] = (ch < C1) ? f2bf(W1[(size_t)ch * (3*E) + k0 + j]) : (unsigned short)0;
        ushort4* dst = reinterpret_cast<ushort4*>(W1t) + (size_t)t * 128 + lane * 2;
        dst[0] = ushort4{v[0],v[1],v[2],v[3]};
        dst[1] = ushort4{v[4],v[5],v[6],v[7]};
    } else if (t < T1 + T2) {
        int tt = t - T1;
        int kk = tt % KT2, nt = tt / KT2;
        int ch = nt * 16 + (lane & 15);
        int rowoff = kk / 7;
        int cbase  = (kk % 7) * 32 + (lane >> 4) * 8;
        #pragma unroll
        for (int j = 0; j < 8; ++j) {
            int c = cbase + j;
            v[j] = (ch < C2 && c < C1) ? f2bf(W2[(size_t)ch * (3*C1) + rowoff * C1 + c])
                                       : (unsigned short)0;
        }
        ushort4* dst = reinterpret_cast<ushort4*>(W2t) + (size_t)tt * 128 + lane * 2;
        dst[0] = ushort4{v[0],v[1],v[2],v[3]};
        dst[1] = ushort4{v[4],v[5],v[6],v[7]};
    } else if (t < T1 + T2 + T3) {
        int tt = t - T1 - T2;
        int kk = tt % KT3, nt = tt / KT3;
        int ch = nt * 16 + (lane & 15);
        int rowoff = kk / 10;
        int cbase  = (kk % 10) * 32 + (lane >> 4) * 8;
        #pragma unroll
        for (int j = 0; j < 8; ++j) {
            int c = cbase + j;
            v[j] = (ch < C3 && c < C2) ? f2bf(W3[(size_t)ch * (3*C2) + rowoff * C2 + c])
                                       : (unsigned short)0;
        }
        ushort4* dst = reinterpret_cast<ushort4*>(W3t) + (size_t)tt * 128 + lane * 2;
        dst[0] = ushort4{v[0],v[1],v[2],v[3]};
        dst[1] = ushort4{v[4],v[5],v[6],v[7]};
    } else {
        int tt = t - T1 - T2 - T3;
        int kk = tt % KTM, nt = tt / KTM;
        int ch = nt * 16 + (lane & 15);
        int kbase = kk * 32 + (lane >> 4) * 8;
        #pragma unroll
        for (int j = 0; j < 8; ++j) {
            int k = kbase + j;
            v[j] = (ch < LIN2 && k < 2648) ? f2bf(Wm[(size_t)ch * 2648 + k])
                                           : (unsigned short)0;
        }
        ushort4* dst = reinterpret_cast<ushort4*>(Wmt) + (size_t)tt * 128 + lane * 2;
        dst[0] = ushort4{v[0],v[1],v[2],v[3]};
        dst[1] = ushort4{v[4],v[5],v[6],v[7]};
    }
}

// ================= conv1: 1 block/batch, wave holds 4 nt x 2 M-tiles ============
__global__ __launch_bounds__(256, 4) void conv1_mfma(
    const int* __restrict__ sent, const float* __restrict__ emb,
    const unsigned short* __restrict__ W1t, const float* __restrict__ bias,
    float* __restrict__ y)
{
    const int b   = blockIdx.x;
    const int tid = threadIdx.x;
    __shared__ unsigned short xs[32 * E];
    __shared__ float rs[32];
    char* xsb = reinterpret_cast<char*>(xs);

    for (int idx = tid; idx < 30 * 128; idx += 256) {
        int r = idx >> 7, c4 = idx & 127;
        int row = sent[b * PAD + r];
        float4 v = reinterpret_cast<const float4*>(emb + (size_t)row * E)[c4];
        ushort4 h;
        h.x = f2bf(v.x); h.y = f2bf(v.y); h.z = f2bf(v.z); h.w = f2bf(v.w);
        int chunk = c4 >> 1, half = c4 & 1;
        int byteoff = r * 1024 + ((chunk ^ (r & 7)) << 4) + half * 8;
        *reinterpret_cast<ushort4*>(xsb + byteoff) = h;
    }
    for (int idx = tid; idx < 2 * 128; idx += 256) {
        int r = 30 + (idx >> 7), c4 = idx & 127;
        int chunk = c4 >> 1, half = c4 & 1;
        int byteoff = r * 1024 + ((chunk ^ (r & 7)) << 4) + half * 8;
        *reinterpret_cast<ushort4*>(xsb + byteoff) = ushort4{0,0,0,0};
    }
    __syncthreads();

    const int wid = tid >> 6, lane = tid & 63;

    for (int r = wid; r < 30; r += 4) {
        float s = 0.f;
        #pragma unroll
        for (int j = 0; j < 8; ++j) {
            int e = lane + 64 * j;
            int chunk = e >> 3, within = e & 7;
            s += bf2f(*reinterpret_cast<unsigned short*>(
                xsb + r * 1024 + ((chunk ^ (r & 7)) << 4) + within * 2));
        }
        for (int off = 32; off; off >>= 1) s += __shfl_down(s, off);
        if (lane == 0) rs[r] = s;
    }
    __syncthreads();

    const int kg = lane >> 4, trow = lane & 15, g = kg;

    const bf16x8* wb = reinterpret_cast<const bf16x8*>(W1t);
    const bf16x8* wp0 = wb + (size_t)((wid     ) * KT1) * 64 + lane;
    const bf16x8* wp1 = wb + (size_t)((wid +  4) * KT1) * 64 + lane;
    const bf16x8* wp2 = wb + (size_t)((wid +  8) * KT1) * 64 + lane;
    const bf16x8* wp3 = wb + (size_t)((wid + 12) * KT1) * 64 + lane;

    f32x4 c00 = {0,0,0,0}, c01 = {0,0,0,0}, c10 = {0,0,0,0}, c11 = {0,0,0,0};
    f32x4 c20 = {0,0,0,0}, c21 = {0,0,0,0}, c30 = {0,0,0,0}, c31 = {0,0,0,0};

    #pragma unroll 4
    for (int kk = 0; kk < KT1; ++kk) {
        int chunk  = (kk & 15) * 4 + kg;
        int rowoff = kk >> 4;
        int r0 = trow + rowoff, r1 = r0 + 16;
        bf16x8 a0 = *reinterpret_cast<const bf16x8*>(
            xsb + r0 * 1024 + ((chunk ^ (r0 & 7)) << 4));
        bf16x8 a1 = *reinterpret_cast<const bf16x8*>(
            xsb + r1 * 1024 + ((chunk ^ (r1 & 7)) << 4));
        bf16x8 b0 = wp0[kk * 64];
        bf16x8 b1 = wp1[kk * 64];
        bf16x8 b2 = wp2[kk * 64];
        bf16x8 b3 = wp3[kk * 64];
        c00 = __builtin_amdgcn_mfma_f32_16x16x32_bf16(a0, b0, c00, 0, 0, 0);
        c01 = __builtin_amdgcn_mfma_f32_16x16x32_bf16(a1, b0, c01, 0, 0, 0);
        c10 = __builtin_amdgcn_mfma_f32_16x16x32_bf16(a0, b1, c10, 0, 0, 0);
        c11 = __builtin_amdgcn_mfma_f32_16x16x32_bf16(a1, b1, c11, 0, 0, 0);
        c20 = __builtin_amdgcn_mfma_f32_16x16x32_bf16(a0, b2, c20, 0, 0, 0);
        c21 = __builtin_amdgcn_mfma_f32_16x16x32_bf16(a1, b2, c21, 0, 0, 0);
        c30 = __builtin_amdgcn_mfma_f32_16x16x32_bf16(a0, b3, c30, 0, 0, 0);
        c31 = __builtin_amdgcn_mfma_f32_16x16x32_bf16(a1, b3, c31, 0, 0, 0);
    }

#define EPI1(NT, CM0, CM1) do {                                                  \
    int ch = (NT) * 16 + trow;                                                   \
    if (ch < C1) {                                                               \
        float bia = bias[ch];                                                    \
        _Pragma("unroll")                                                        \
        for (int hf = 0; hf < 2; ++hf) {                                         \
            { int t0 = 4 * g + 2 * hf; int tp = t0 >> 1;                         \
              float v0 = CM0[2*hf] + bia, v1 = CM0[2*hf+1] + bia;                \
              v0 = LEAKY(v0); v1 = LEAKY(v1);                                    \
              if (rs[t0] + rs[t0+1] + rs[t0+2] == 0.f) v0 = 0.f;                 \
              if (rs[t0+1] + rs[t0+2] + rs[t0+3] == 0.f) v1 = 0.f;               \
              y[(size_t)(b * 14 + tp) * C1 + ch] = fmaxf(v0, v1); }              \
            { int t0 = 16 + 4 * g + 2 * hf; int tp = t0 >> 1;                    \
              if (tp < 14) {                                                     \
                float v0 = CM1[2*hf] + bia, v1 = CM1[2*hf+1] + bia;              \
                v0 = LEAKY(v0); v1 = LEAKY(v1);                                  \
                if (rs[t0] + rs[t0+1] + rs[t0+2] == 0.f) v0 = 0.f;               \
                if (rs[t0+1] + rs[t0+2] + rs[t0+3] == 0.f) v1 = 0.f;             \
                y[(size_t)(b * 14 + tp) * C1 + ch] = fmaxf(v0, v1); } }          \
        }                                                                        \
    }                                                                            \
} while (0)

    EPI1(wid,      c00, c01);
    EPI1(wid + 4,  c10, c11);
    EPI1(wid + 8,  c20, c21);
    EPI1(wid + 12, c30, c31);
#undef EPI1
}

// ================= conv2: 1 block/batch, wave holds 5 nt =======================
__global__ __launch_bounds__(256) void conv2_mfma(
    const float* __restrict__ x, const unsigned short* __restrict__ Wt,
    const float* __restrict__ bias, float* __restrict__ y)
{
    const int b   = blockIdx.x;
    const int tid = threadIdx.x;
    __shared__ unsigned short xs[18 * 256];
    __shared__ float rs[18];
    char* xsb = reinterpret_cast<char*>(xs);

    for (int idx = tid; idx < 18 * 32; idx += 256) {
        int r = idx >> 5, ck = idx & 31;
        ushort4 lo = {0,0,0,0}, hi = {0,0,0,0};
        if (r < 14 && ck < 25) {
            const float4* src = reinterpret_cast<const float4*>(
                x + ((size_t)b * 14 + r) * C1 + ck * 8);
            float4 a = src[0], c = src[1];
            lo.x=f2bf(a.x); lo.y=f2bf(a.y); lo.z=f2bf(a.z); lo.w=f2bf(a.w);
            hi.x=f2bf(c.x); hi.y=f2bf(c.y); hi.z=f2bf(c.z); hi.w=f2bf(c.w);
        }
        int bo_ = r * 512 + ((ck ^ (r & 7)) << 4);
        *reinterpret_cast<ushort4*>(xsb + bo_)     = lo;
        *reinterpret_cast<ushort4*>(xsb + bo_ + 8) = hi;
    }
    __syncthreads();

    const int wid = tid >> 6, lane = tid & 63;
    const int kg = lane >> 4, trow = lane & 15, g = kg;

    for (int r = wid; r < 14; r += 4) {
        float s = 0.f;
        #pragma unroll
        for (int j = 0; j < 4; ++j) {
            int e = lane + 64 * j;
            int chunk = e >> 3, within = e & 7;
            s += bf2f(*reinterpret_cast<unsigned short*>(
                xsb + r * 512 + ((chunk ^ (r & 7)) << 4) + within * 2));
        }
        for (int off = 32; off; off >>= 1) s += __shfl_down(s, off);
        if (lane == 0) rs[r] = s;
    }
    __syncthreads();

    const bf16x8* wb = reinterpret_cast<const bf16x8*>(Wt);
    const bf16x8* wp0 = wb + (size_t)((wid     ) * KT2) * 64 + lane;
    const bf16x8* wp1 = wb + (size_t)((wid +  4) * KT2) * 64 + lane;
    const bf16x8* wp2 = wb + (size_t)((wid +  8) * KT2) * 64 + lane;
    const bf16x8* wp3 = wb + (size_t)((wid + 12) * KT2) * 64 + lane;
    const bf16x8* wp4 = wb + (size_t)((wid + 16) * KT2) * 64 + lane;

    f32x4 c0 = {0,0,0,0}, c1 = {0,0,0,0}, c2 = {0,0,0,0}, c3 = {0,0,0,0}, c4 = {0,0,0,0};

    int kidx = 0;
    #pragma unroll
    for (int rowoff = 0; rowoff < 3; ++rowoff) {
        #pragma unroll
        for (int cc = 0; cc < 7; ++cc, ++kidx) {
            int r0 = trow + rowoff;
            int chunk = cc * 4 + kg;
            bf16x8 a = *reinterpret_cast<const bf16x8*>(
                xsb + r0 * 512 + ((chunk ^ (r0 & 7)) << 4));
            bf16x8 b0 = wp0[kidx * 64];
            bf16x8 b1 = wp1[kidx * 64];
            bf16x8 b2 = wp2[kidx * 64];
            bf16x8 b3 = wp3[kidx * 64];
            bf16x8 b4 = wp4[kidx * 64];
            c0 = __builtin_amdgcn_mfma_f32_16x16x32_bf16(a, b0, c0, 0, 0, 0);
            c1 = __builtin_amdgcn_mfma_f32_16x16x32_bf16(a, b1, c1, 0, 0, 0);
            c2 = __builtin_amdgcn_mfma_f32_16x16x32_bf16(a, b2, c2, 0, 0, 0);
            c3 = __builtin_amdgcn_mfma_f32_16x16x32_bf16(a, b3, c3, 0, 0, 0);
            c4 = __builtin_amdgcn_mfma_f32_16x16x32_bf16(a, b4, c4, 0, 0, 0);
        }
    }

#define EPI2(NT, CM) do {                                                        \
    int ch = (NT) * 16 + trow;                                                   \
    if (ch < C2) {                                                               \
        float bia = bias[ch];                                                    \
        _Pragma("unroll")                                                        \
        for (int hf = 0; hf < 2; ++hf) {                                         \
            int t0 = 4 * g + 2 * hf;                                             \
            if (t0 < 12) {                                                       \
                float v0 = LEAKY(CM[2*hf]   + bia);                              \
                float v1 = LEAKY(CM[2*hf+1] + bia);                              \
                if (rs[t0] + rs[t0+1] + rs[t0+2] == 0.f) v0 = 0.f;               \
                if (rs[t0+1] + rs[t0+2] + rs[t0+3] == 0.f) v1 = 0.f;             \
                y[((size_t)b * 6 + (t0 >> 1)) * C2 + ch] = fmaxf(v0, v1);        \
            }                                                                    \
        }                                                                        \
    }                                                                            \
} while (0)

    EPI2(wid,      c0);
    EPI2(wid + 4,  c1);
    EPI2(wid + 8,  c2);
    EPI2(wid + 12, c3);
    EPI2(wid + 16, c4);
#undef EPI2
}

// ================= conv3: 1 block / 4 batches, wave holds 5 nt ==================
__global__ __launch_bounds__(256) void conv3_mfma(
    const float* __restrict__ x, const unsigned short* __restrict__ Wt,
    const float* __restrict__ bias, float* __restrict__ y)
{
    const int b0  = blockIdx.x * 4;
    const int tid = threadIdx.x;
    __shared__ unsigned short xs[24 * 320];
    __shared__ float rs[24];
    char* xsb = reinterpret_cast<char*>(xs);

    for (int idx = tid; idx < 24 * 40; idx += 256) {
        int r = idx / 40, ck = idx % 40;
        int c0 = ck * 8;
        ushort4 lo = {0,0,0,0}, hi = {0,0,0,0};
        const float* row = x + ((size_t)b0 * 6 + r) * C2;
        if (c0 + 8 <= C2) {
            const float4* src = reinterpret_cast<const float4*>(row + c0);
            float4 a = src[0], c = src[1];
            lo.x=f2bf(a.x); lo.y=f2bf(a.y); lo.z=f2bf(a.z); lo.w=f2bf(a.w);
            hi.x=f2bf(c.x); hi.y=f2bf(c.y); hi.z=f2bf(c.z); hi.w=f2bf(c.w);
        } else if (c0 < C2) {
            unsigned short v[8];
            #pragma unroll
            for (int j = 0; j < 8; ++j)
                v[j] = (c0 + j < C2) ? f2bf(row[c0 + j]) : (unsigned short)0;
            lo = ushort4{v[0],v[1],v[2],v[3]};
            hi = ushort4{v[4],v[5],v[6],v[7]};
        }
        int bo_ = r * 640 + ((ck ^ (r & 7)) << 4);
        *reinterpret_cast<ushort4*>(xsb + bo_)     = lo;
        *reinterpret_cast<ushort4*>(xsb + bo_ + 8) = hi;
    }
    __syncthreads();

    const int wid = tid >> 6, lane = tid & 63;
    const int kg = lane >> 4, trow = lane & 15, g = kg;

    for (int r = wid; r < 24; r += 4) {
        float s = 0.f;
        #pragma unroll
        for (int j = 0; j < 5; ++j) {
            int e = lane + 64 * j;
            int chunk = e >> 3, within = e & 7;
            s += bf2f(*reinterpret_cast<unsigned short*>(
                xsb + r * 640 + ((chunk ^ (r & 7)) << 4) + within * 2));
        }
        for (int off = 32; off; off >>= 1) s += __shfl_down(s, off);
        if (lane == 0) rs[r] = s;
    }
    __syncthreads();

    const int rbase = 6 * (trow >> 2) + (trow & 3);

    const bf16x8* wb = reinterpret_cast<const bf16x8*>(Wt);
    const bf16x8* wp0 = wb + (size_t)((wid     ) * KT3) * 64 + lane;
    const bf16x8* wp1 = wb + (size_t)((wid +  4) * KT3) * 64 + lane;
    const bf16x8* wp2 = wb + (size_t)((wid +  8) * KT3) * 64 + lane;
    const bf16x8* wp3 = wb + (size_t)((wid + 12) * KT3) * 64 + lane;
    const bf16x8* wp4 = wb + (size_t)((wid + 16) * KT3) * 64 + lane;

    f32x4 c0 = {0,0,0,0}, c1 = {0,0,0,0}, c2 = {0,0,0,0}, c3 = {0,0,0,0}, c4 = {0,0,0,0};

    int kidx = 0;
    #pragma unroll
    for (int rowoff = 0; rowoff < 3; ++rowoff) {
        #pragma unroll
        for (int cc = 0; cc < 10; ++cc, ++kidx) {
            int r0 = rbase + rowoff;
            int chunk = cc * 4 + kg;
            bf16x8 a = *reinterpret_cast<const bf16x8*>(
                xsb + r0 * 640 + ((chunk ^ (r0 & 7)) << 4));
            bf16x8 b0 = wp0[kidx * 64];
            bf16x8 b1 = wp1[kidx * 64];
            bf16x8 b2 = wp2[kidx * 64];
            bf16x8 b3 = wp3[kidx * 64];
            bf16x8 b4 = wp4[kidx * 64];
            c0 = __builtin_amdgcn_mfma_f32_16x16x32_bf16(a, b0, c0, 0, 0, 0);
            c1 = __builtin_amdgcn_mfma_f32_16x16x32_bf16(a, b1, c1, 0, 0, 0);
            c2 = __builtin_amdgcn_mfma_f32_16x16x32_bf16(a, b2, c2, 0, 0, 0);
            c3 = __builtin_amdgcn_mfma_f32_16x16x32_bf16(a, b3, c3, 0, 0, 0);
            c4 = __builtin_amdgcn_mfma_f32_16x16x32_bf16(a, b4, c4, 0, 0, 0);
        }
    }

#define EPI3(NT, CM) do {                                                        \
    int ch = (NT) * 16 + trow;                                                   \
    if (ch < C3) {                                                               \
        float bia = bias[ch];                                                    \
        _Pragma("unroll")                                                        \
        for (int tp = 0; tp < 2; ++tp) {                                         \
            int rb = g * 6 + 2 * tp;                                             \
            float v0 = LEAKY(CM[2*tp]   + bia);                                  \
            float v1 = LEAKY(CM[2*tp+1] + bia);                                  \
            if (rs[rb] + rs[rb+1] + rs[rb+2] == 0.f) v0 = 0.f;                   \
            if (rs[rb+1] + rs[rb+2] + rs[rb+3] == 0.f) v1 = 0.f;                 \
            y[((size_t)(b0 + g) * 2 + tp) * C3 + ch] = fmaxf(v0, v1);            \
        }                                                                        \
    }                                                                            \
} while (0)

    EPI3(wid,      c0);
    EPI3(wid + 4,  c1);
    EPI3(wid + 8,  c2);
    EPI3(wid + 12, c3);
    EPI3(wid + 16, c4);
#undef EPI3
}

// ================= feats concat: [y3 | image] -> bf16 [B][2656] =================
__global__ __launch_bounds__(256) void concat_feats(
    const float* __restrict__ y3, const float* __restrict__ img,
    unsigned short* __restrict__ feats)
{
    const int b = blockIdx.x;
    for (int ck = threadIdx.x; ck < FK / 8; ck += 256) {
        int c0 = ck * 8;
        ushort4 lo = {0,0,0,0}, hi = {0,0,0,0};
        const float4* src = nullptr;
        if (c0 + 8 <= 600)       src = reinterpret_cast<const float4*>(y3 + (size_t)b*600 + c0);
        else if (c0 + 8 <= 2648) src = reinterpret_cast<const float4*>(img + (size_t)b*IMG + (c0-600));
        if (src) {
            float4 a = src[0], c = src[1];
            lo.x=f2bf(a.x); lo.y=f2bf(a.y); lo.z=f2bf(a.z); lo.w=f2bf(a.w);
            hi.x=f2bf(c.x); hi.y=f2bf(c.y); hi.z=f2bf(c.z); hi.w=f2bf(c.w);
        }
        ushort4* dst = reinterpret_cast<ushort4*>(feats + (size_t)b * FK + c0);
        dst[0] = lo; dst[1] = hi;
    }
}

// ================= final GEMM: 1 wave/block, wave = (mt, 7 nts) =================
__global__ __launch_bounds__(64) void final_mfma(
    const unsigned short* __restrict__ feats, const unsigned short* __restrict__ Wmt,
    const float* __restrict__ bm, float* __restrict__ h)
{
    const int lane = threadIdx.x;
    const int bid  = blockIdx.x;
    const int mt = bid >> 2, q = bid & 3;
    const int kg = lane >> 4, trow = lane & 15, g = kg;
    const int m0 = mt * 16;

    const bf16x8* ap = reinterpret_cast<const bf16x8*>(feats)
                       + (size_t)(m0 + trow) * (FK / 8) + kg;
    const bf16x8* wb = reinterpret_cast<const bf16x8*>(Wmt);
    const bf16x8* wp0 = wb + (size_t)((q     ) * KTM) * 64 + lane;
    const bf16x8* wp1 = wb + (size_t)((q +  4) * KTM) * 64 + lane;
    const bf16x8* wp2 = wb + (size_t)((q +  8) * KTM) * 64 + lane;
    const bf16x8* wp3 = wb + (size_t)((q + 12) * KTM) * 64 + lane;
    const bf16x8* wp4 = wb + (size_t)((q + 16) * KTM) * 64 + lane;
    const bf16x8* wp5 = wb + (size_t)((q + 20) * KTM) * 64 + lane;
    const bf16x8* wp6 = wb + (size_t)((q + 24) * KTM) * 64 + lane;

    f32x4 c0 = {0,0,0,0}, c1 = {0,0,0,0}, c2 = {0,0,0,0}, c3 = {0,0,0,0};
    f32x4 c4 = {0,0,0,0}, c5 = {0,0,0,0}, c6 = {0,0,0,0};

    #pragma unroll 2
    for (int kk = 0; kk < KTM; ++kk) {
        bf16x8 a  = ap[kk * 4];
        bf16x8 b0 = wp0[kk * 64];
        bf16x8 b1 = wp1[kk * 64];
        bf16x8 b2 = wp2[kk * 64];
        bf16x8 b3 = wp3[kk * 64];
        bf16x8 b4 = wp4[kk * 64];
        bf16x8 b5 = wp5[kk * 64];
        bf16x8 b6 = wp6[kk * 64];
        c0 = __builtin_amdgcn_mfma_f32_16x16x32_bf16(a, b0, c0, 0, 0, 0);
        c1 = __builtin_amdgcn_mfma_f32_16x16x32_bf16(a, b1, c1, 0, 0, 0);
        c2 = __builtin_amdgcn_mfma_f32_16x16x32_bf16(a, b2, c2, 0, 0, 0);
        c3 = __builtin_amdgcn_mfma_f32_16x16x32_bf16(a, b3, c3, 0, 0, 0);
        c4 = __builtin_amdgcn_mfma_f32_16x16x32_bf16(a, b4, c4, 0, 0, 0);
        c5 = __builtin_amdgcn_mfma_f32_16x16x32_bf16(a, b5, c5, 0, 0, 0);
        c6 = __builtin_amdgcn_mfma_f32_16x16x32_bf16(a, b6, c6, 0, 0, 0);
    }

#define EPIM(NT, CM) do {                                                        \
    int ch = (NT) * 16 + trow;                                                   \
    if (ch < LIN2) {                                                             \
        float bia = bm[ch];                                                      \
        _Pragma("unroll")                                                        \
        for (int reg = 0; reg < 4; ++reg) {                                      \
            float v = LEAKY(CM[reg] + bia);                                      \
            h[(size_t)(m0 + 4 * g + reg) * LIN2 + ch] = v;                       \
        }                                                                        \
    }                                                                            \
} while (0)

    EPIM(q,      c0);
    EPIM(q + 4,  c1);
    EPIM(q + 8,  c2);
    EPIM(q + 12, c3);
    EPIM(q + 16, c4);
    EPIM(q + 20, c5);
    EPIM(q + 24, c6);
#undef EPIM
}

// ================= out[b] = h[b] . Wo + bo ======================================
__global__ __launch_bounds__(256) void final_reduce(
    const float* __restrict__ h, const float* __restrict__ Wo,
    const float* __restrict__ bo, float* __restrict__ out)
{
    const int tid = threadIdx.x;
    const int wid = tid >> 6, lane = tid & 63;
    const int b = blockIdx.x * 4 + wid;
    float s = 0.f;
    #pragma unroll
    for (int j = 0; j < 7; ++j) {
        int o = lane + 64 * j;
        if (o < LIN2) s += h[(size_t)b * LIN2 + o] * Wo[o];
    }
    for (int off = 32; off; off >>= 1) s += __shfl_down(s, off);
    if (lane == 0) out[b] = s + bo[0];
}

extern "C" void kernel_launch(void* const* d_in, const int* in_sizes, int n_in,
                              void* d_out, int out_size, void* d_ws, size_t ws_size,
                              hipStream_t stream) {
    const float* image = (const float*)d_in[0];
    const int*   sent  = (const int*)  d_in[1];
    const float* emb   = (const float*)d_in[2];
    const float* W1    = (const float*)d_in[3];
    const float* b1    = (const float*)d_in[4];
    const float* W2    = (const float*)d_in[5];
    const float* b2    = (const float*)d_in[6];
    const float* W3    = (const float*)d_in[7];
    const float* b3    = (const float*)d_in[8];
    const float* Wm    = (const float*)d_in[9];
    const float* bm    = (const float*)d_in[10];
    const float* Wo    = (const float*)d_in[11];
    const float* bo    = (const float*)d_in[12];
    float* out = (float*)d_out;

    float* y1 = (float*)d_ws;                          // 2,867,200 f
    float* y2 = y1 + 2867200;                          // 1,843,200 f
    float* y3 = y2 + 1843200;                          //   614,400 f
    unsigned short* W1t = (unsigned short*)(y3 + 614400);   // T1*512
    unsigned short* W2t = W1t + (size_t)T1 * 512;            // T2*512
    unsigned short* W3t = W2t + (size_t)T2 * 512;            // T3*512
    unsigned short* Wmt = W3t + (size_t)T3 * 512;            // TM*512
    unsigned short* feats = (unsigned short*)y1;             // reuse y1 region
    float* h = y2;                                           // reuse y2 region

    convert_all<<<(TTOT * 64 + 255) / 256, 256, 0, stream>>>(
        W1, W2, W3, Wm, W1t, W2t, W3t, Wmt);

    conv1_mfma<<<B_, 256, 0, stream>>>(sent, emb, W1t, b1, y1);
    conv2_mfma<<<B_, 256, 0, stream>>>(y1, W2t, b2, y2);
    conv3_mfma<<<B_/4, 256, 0, stream>>>(y2, W3t, b3, y3);
    concat_feats<<<B_, 256, 0, stream>>>(y3, image, feats);
    final_mfma<<<64 * 4, 64, 0, stream>>>(feats, Wmt, bm, h);
    final_reduce<<<B_/4, 256, 0, stream>>>(h, Wo, bo, out);
}